// Round 5
// baseline (327.725 us; speedup 1.0000x reference)
//
#include <hip/hip_runtime.h>

// LQActiv forward: 2-bit quantization + least-squares basis refit.
// Output layout: [N floats wq][2 floats new_basis].
//
// Round 5: BISECT ROUND. Time is pinned at ~250-295us across all cache
// policies / ILP depths, always ~= counted_traffic / 2.4 TB/s. Three probe
// dispatches isolate the memory streams before the real kernel runs:
//   P1 copy_probe<false>: plain cached float4 copy (m13 replica).
//   P2 copy_probe<true>:  NT float4 copy.
//   P3 reduce_probe:      NT read-only sum (write ~0) -> pure-read ceiling.
// The real lq_main (round-3 structure, best so far) runs LAST so d_out is
// correct. All dispatches deterministic; probes write d_out/d_ws regions
// that are later overwritten or unused.

#define NBLOCKS 2048
#define NTHREADS 256

typedef float fvec4 __attribute__((ext_vector_type(4)));

// ---------------- probes ----------------

template <bool NT>
__global__ __launch_bounds__(NTHREADS) void copy_probe(
    const fvec4* __restrict__ in, fvec4* __restrict__ out, int n4) {
  int i = blockIdx.x * blockDim.x + threadIdx.x;
  const int stride = gridDim.x * blockDim.x;
  for (; i < n4; i += stride) {
    if (NT) {
      fvec4 v = __builtin_nontemporal_load(&in[i]);
      __builtin_nontemporal_store(v, &out[i]);
    } else {
      out[i] = in[i];
    }
  }
}

__global__ __launch_bounds__(NTHREADS) void reduce_probe(
    const fvec4* __restrict__ in, float* __restrict__ sums, int n4) {
  float s = 0.f;
  int i = blockIdx.x * blockDim.x + threadIdx.x;
  const int stride = gridDim.x * blockDim.x;
  for (; i < n4; i += stride) {
    fvec4 v = __builtin_nontemporal_load(&in[i]);
    s += (v.x + v.y) + (v.z + v.w);
  }
  for (int off = 32; off; off >>= 1) s += __shfl_down(s, off);
  __shared__ float red[NTHREADS / 64];
  if ((threadIdx.x & 63) == 0) red[threadIdx.x >> 6] = s;
  __syncthreads();
  if (threadIdx.x == 0) {
    float t = 0.f;
#pragma unroll
    for (int w = 0; w < NTHREADS / 64; ++w) t += red[w];
    sums[blockIdx.x] = t;
  }
}

// ---------------- real kernels (round-3 structure) ----------------

__global__ __launch_bounds__(NTHREADS) void lq_main(
    const float* __restrict__ x, const float* __restrict__ basis,
    float* __restrict__ out, float* __restrict__ partials,
    int n, int n4) {
  const float v0 = basis[0], v1 = basis[1];
  float lev[4] = {-v0 - v1, -v0 + v1, v0 - v1, v0 + v1};
  float e0[4] = {-1.f, -1.f, 1.f, 1.f};
  float e1[4] = {-1.f, 1.f, -1.f, 1.f};
#define CSWAP(i, j)                                                   \
  if (lev[i] > lev[j]) {                                              \
    float t = lev[i]; lev[i] = lev[j]; lev[j] = t;                    \
    t = e0[i]; e0[i] = e0[j]; e0[j] = t;                              \
    t = e1[i]; e1[i] = e1[j]; e1[j] = t;                              \
  }
  CSWAP(0, 1) CSWAP(2, 3) CSWAP(0, 2) CSWAP(1, 3) CSWAP(1, 2)
#undef CSWAP
  const float Q0 = lev[0], Q1 = lev[1], Q2 = lev[2], Q3 = lev[3];
  const float A0 = e0[0], A1 = e0[1], A2 = e0[2], A3 = e0[3];
  const float B0 = e1[0], B1 = e1[1], B2 = e1[2], B3 = e1[3];
  const float T0 = 0.5f * (Q0 + Q1);
  const float T1 = 0.5f * (Q1 + Q2);
  const float T2 = 0.5f * (Q2 + Q3);

  float s01 = 0.f, sb0 = 0.f, sb1 = 0.f;

  const int tid = blockIdx.x * blockDim.x + threadIdx.x;
  const int stride = gridDim.x * blockDim.x;

  auto proc = [&](float w) -> float {
    float q = Q0, b0 = A0, b1 = B0;
    if (w > T0) { q = Q1; b0 = A1; b1 = B1; }
    if (w > T1) { q = Q2; b0 = A2; b1 = B2; }
    if (w > T2) { q = Q3; b0 = A3; b1 = B3; }
    s01 += b0 * b1;
    sb0 = fmaf(b0, w, sb0);
    sb1 = fmaf(b1, w, sb1);
    return q;
  };

  const fvec4* __restrict__ x4 = (const fvec4*)x;
  fvec4* __restrict__ o4 = (fvec4*)out;

  int i = tid;
  for (; i + stride < n4; i += 2 * stride) {
    fvec4 wa = __builtin_nontemporal_load(&x4[i]);
    fvec4 wb = __builtin_nontemporal_load(&x4[i + stride]);
    fvec4 qa, qb;
    qa.x = proc(wa.x);
    qa.y = proc(wa.y);
    qa.z = proc(wa.z);
    qa.w = proc(wa.w);
    qb.x = proc(wb.x);
    qb.y = proc(wb.y);
    qb.z = proc(wb.z);
    qb.w = proc(wb.w);
    __builtin_nontemporal_store(qa, &o4[i]);
    __builtin_nontemporal_store(qb, &o4[i + stride]);
  }
  for (; i < n4; i += stride) {
    fvec4 w = __builtin_nontemporal_load(&x4[i]);
    fvec4 q;
    q.x = proc(w.x);
    q.y = proc(w.y);
    q.z = proc(w.z);
    q.w = proc(w.w);
    __builtin_nontemporal_store(q, &o4[i]);
  }
  for (int k = n4 * 4 + tid; k < n; k += stride) {
    out[k] = proc(x[k]);
  }

  for (int off = 32; off; off >>= 1) {
    s01 += __shfl_down(s01, off);
    sb0 += __shfl_down(sb0, off);
    sb1 += __shfl_down(sb1, off);
  }
  __shared__ float red[3][NTHREADS / 64];
  const int lane = threadIdx.x & 63;
  const int wid = threadIdx.x >> 6;
  if (lane == 0) {
    red[0][wid] = s01;
    red[1][wid] = sb0;
    red[2][wid] = sb1;
  }
  __syncthreads();
  if (threadIdx.x == 0) {
    float r01 = 0.f, rb0 = 0.f, rb1 = 0.f;
#pragma unroll
    for (int w = 0; w < NTHREADS / 64; ++w) {
      r01 += red[0][w];
      rb0 += red[1][w];
      rb1 += red[2][w];
    }
    partials[3 * blockIdx.x + 0] = r01;
    partials[3 * blockIdx.x + 1] = rb0;
    partials[3 * blockIdx.x + 2] = rb1;
  }
}

__global__ __launch_bounds__(NTHREADS) void lq_final(
    const float* __restrict__ partials, const float* __restrict__ basis,
    float* __restrict__ out_basis, int n, int nparts) {
  double s01 = 0.0, sb0 = 0.0, sb1 = 0.0;
  for (int i = threadIdx.x; i < nparts; i += blockDim.x) {
    s01 += (double)partials[3 * i + 0];
    sb0 += (double)partials[3 * i + 1];
    sb1 += (double)partials[3 * i + 2];
  }
  for (int off = 32; off; off >>= 1) {
    s01 += __shfl_down(s01, off);
    sb0 += __shfl_down(sb0, off);
    sb1 += __shfl_down(sb1, off);
  }
  __shared__ double red[3][NTHREADS / 64];
  const int lane = threadIdx.x & 63;
  const int wid = threadIdx.x >> 6;
  if (lane == 0) {
    red[0][wid] = s01;
    red[1][wid] = sb0;
    red[2][wid] = sb1;
  }
  __syncthreads();
  if (threadIdx.x == 0) {
    double S01 = 0.0, Sb0 = 0.0, Sb1 = 0.0;
#pragma unroll
    for (int w = 0; w < NTHREADS / 64; ++w) {
      S01 += red[0][w];
      Sb0 += red[1][w];
      Sb1 += red[2][w];
    }
    const double N = (double)n;
    const double det = N * N - S01 * S01;
    const double nv0 = (N * Sb0 - S01 * Sb1) / det;
    const double nv1 = (N * Sb1 - S01 * Sb0) / det;
    out_basis[0] = (float)(0.9 * (double)basis[0] + 0.1 * nv0);
    out_basis[1] = (float)(0.9 * (double)basis[1] + 0.1 * nv1);
  }
}

extern "C" void kernel_launch(void* const* d_in, const int* in_sizes, int n_in,
                              void* d_out, int out_size, void* d_ws, size_t ws_size,
                              hipStream_t stream) {
  const float* x = (const float*)d_in[0];
  const float* basis = (const float*)d_in[1];
  float* out = (float*)d_out;
  const int n = in_sizes[0];
  float* partials = (float*)d_ws;                          // 24 KB
  float* psums = (float*)((char*)d_ws + 24 * 1024);        // 8 KB

  const int n4 = n / 4;
  const fvec4* x4 = (const fvec4*)x;
  fvec4* o4 = (fvec4*)out;

  // --- probes (results overwritten / unused; deterministic) ---
  copy_probe<false><<<NBLOCKS, NTHREADS, 0, stream>>>(x4, o4, n4);
  copy_probe<true><<<NBLOCKS, NTHREADS, 0, stream>>>(x4, o4, n4);
  if (ws_size >= 32 * 1024) {
    reduce_probe<<<NBLOCKS, NTHREADS, 0, stream>>>(x4, psums, n4);
  }

  // --- real computation (last, so d_out is correct) ---
  lq_main<<<NBLOCKS, NTHREADS, 0, stream>>>(x, basis, out, partials, n, n4);
  lq_final<<<1, NTHREADS, 0, stream>>>(partials, basis, out + n, n, NBLOCKS);
}

// Round 6
// 138.518 us; speedup vs baseline: 2.3659x; 2.3659x over previous
//
#include <hip/hip_runtime.h>

// LQActiv forward: 2-bit quantization + least-squares basis refit.
// Output layout: [N floats wq][2 floats new_basis].
//
// Round 6: kill the suspected scratch-spill. Round-5 bisect: copy/reduce
// probes with IDENTICAL loads/stores ran ~6.4 TB/s; lq_main with its
// 12-value select web ran 2.4 TB/s with 2x FETCH / 3.6x WRITE inflation
// and VGPR_Count(24) < live-value count -> sorted lev/e0/e1 arrays likely
// demoted to scratch; per-element scratch reloads = the hidden traffic.
//
// New structure: in-loop state is only {T0,T1,T2,Q0,Q1,Q2,Q3} + 7 raw
// accumulators (c0,c1,c2 = sum tj; sw = sum w; sw0..2 = sum tj*w), using
// threshold monotonicity. All encoding algebra (S01, Sb0, Sb1 via
// telescoping over the one-hot) moves to lq_final, which re-derives the
// sorted encodings from basis. Loop shape = the fast copy probe's.

#define NBLOCKS 2048
#define NTHREADS 256

typedef float fvec4 __attribute__((ext_vector_type(4)));

__global__ __launch_bounds__(NTHREADS) void lq_main(
    const float* __restrict__ x, const float* __restrict__ basis,
    float* __restrict__ out, float* __restrict__ partials,
    int n, int n4, int nblocks) {
  // sorted quantization levels (values only; encodings not needed here)
  const float v0 = basis[0], v1 = basis[1];
  float lev[4] = {-v0 - v1, -v0 + v1, v0 - v1, v0 + v1};
#define CSWAP(i, j)                                          \
  if (lev[i] > lev[j]) { float t = lev[i]; lev[i] = lev[j]; lev[j] = t; }
  CSWAP(0, 1) CSWAP(2, 3) CSWAP(0, 2) CSWAP(1, 3) CSWAP(1, 2)
#undef CSWAP
  const float Q0 = lev[0], Q1 = lev[1], Q2 = lev[2], Q3 = lev[3];
  const float T0 = 0.5f * (Q0 + Q1);
  const float T1 = 0.5f * (Q1 + Q2);
  const float T2 = 0.5f * (Q2 + Q3);

  // raw accumulators (counts fit easily in int; ~49 elements/thread)
  int c0 = 0, c1 = 0, c2 = 0;
  float sw = 0.f, sw0 = 0.f, sw1 = 0.f, sw2 = 0.f;

  auto proc = [&](float w) -> float {
    const bool t0 = w > T0;
    const bool t1 = w > T1;
    const bool t2 = w > T2;
    c0 += t0;
    c1 += t1;
    c2 += t2;
    sw += w;
    sw0 += t0 ? w : 0.f;
    sw1 += t1 ? w : 0.f;
    sw2 += t2 ? w : 0.f;
    float q = t0 ? Q1 : Q0;   // thresholds are monotone, so chained
    q = t1 ? Q2 : q;          // selects give q = Qlevels[t0+t1+t2]
    q = t2 ? Q3 : q;
    return q;
  };

  const fvec4* __restrict__ x4 = (const fvec4*)x;
  fvec4* __restrict__ o4 = (fvec4*)out;

  const int tid = blockIdx.x * blockDim.x + threadIdx.x;
  const int stride = gridDim.x * blockDim.x;

  // exact copy-probe loop shape: 1-deep grid-stride, NT load + NT store
  for (int i = tid; i < n4; i += stride) {
    fvec4 w = __builtin_nontemporal_load(&x4[i]);
    fvec4 q;
    q.x = proc(w.x);
    q.y = proc(w.y);
    q.z = proc(w.z);
    q.w = proc(w.w);
    __builtin_nontemporal_store(q, &o4[i]);
  }
  // scalar tail (N here is divisible by 4; kept for safety)
  for (int k = n4 * 4 + tid; k < n; k += stride) {
    out[k] = proc(x[k]);
  }

  // block reduction: wave shfl, then LDS across the 4 waves
  float f0 = (float)c0, f1 = (float)c1, f2 = (float)c2;
  for (int off = 32; off; off >>= 1) {
    f0 += __shfl_down(f0, off);
    f1 += __shfl_down(f1, off);
    f2 += __shfl_down(f2, off);
    sw += __shfl_down(sw, off);
    sw0 += __shfl_down(sw0, off);
    sw1 += __shfl_down(sw1, off);
    sw2 += __shfl_down(sw2, off);
  }
  __shared__ float red[7][NTHREADS / 64];
  const int lane = threadIdx.x & 63;
  const int wid = threadIdx.x >> 6;
  if (lane == 0) {
    red[0][wid] = f0;
    red[1][wid] = f1;
    red[2][wid] = f2;
    red[3][wid] = sw;
    red[4][wid] = sw0;
    red[5][wid] = sw1;
    red[6][wid] = sw2;
  }
  __syncthreads();
  if (threadIdx.x < 7) {
    // thread k reduces quantity k across the 4 waves (static-free indexing
    // into LDS is fine; LDS is memory, not registers)
    float r = 0.f;
#pragma unroll
    for (int w = 0; w < NTHREADS / 64; ++w) r += red[threadIdx.x][w];
    partials[7 * blockIdx.x + threadIdx.x] = r;
  }
}

__global__ __launch_bounds__(NTHREADS) void lq_final(
    const float* __restrict__ partials, const float* __restrict__ basis,
    float* __restrict__ out_basis, int n, int nparts) {
  // reduce 7 columns in f64 (named scalars; no runtime-indexed arrays)
  double C0 = 0, C1 = 0, C2 = 0, SW = 0, SW0 = 0, SW1 = 0, SW2 = 0;
  for (int i = threadIdx.x; i < nparts; i += blockDim.x) {
    C0 += (double)partials[7 * i + 0];
    C1 += (double)partials[7 * i + 1];
    C2 += (double)partials[7 * i + 2];
    SW += (double)partials[7 * i + 3];
    SW0 += (double)partials[7 * i + 4];
    SW1 += (double)partials[7 * i + 5];
    SW2 += (double)partials[7 * i + 6];
  }
  for (int off = 32; off; off >>= 1) {
    C0 += __shfl_down(C0, off);
    C1 += __shfl_down(C1, off);
    C2 += __shfl_down(C2, off);
    SW += __shfl_down(SW, off);
    SW0 += __shfl_down(SW0, off);
    SW1 += __shfl_down(SW1, off);
    SW2 += __shfl_down(SW2, off);
  }
  __shared__ double red[7][NTHREADS / 64];
  const int lane = threadIdx.x & 63;
  const int wid = threadIdx.x >> 6;
  if (lane == 0) {
    red[0][wid] = C0;
    red[1][wid] = C1;
    red[2][wid] = C2;
    red[3][wid] = SW;
    red[4][wid] = SW0;
    red[5][wid] = SW1;
    red[6][wid] = SW2;
  }
  __syncthreads();
  if (threadIdx.x == 0) {
    double c0 = 0, c1 = 0, c2 = 0, s = 0, s0 = 0, s1 = 0, s2 = 0;
#pragma unroll
    for (int w = 0; w < NTHREADS / 64; ++w) {
      c0 += red[0][w];
      c1 += red[1][w];
      c2 += red[2][w];
      s += red[3][w];
      s0 += red[4][w];
      s1 += red[5][w];
      s2 += red[6][w];
    }
    // re-derive sorted levels + encodings from basis
    const float v0 = basis[0], v1 = basis[1];
    float lev[4] = {-v0 - v1, -v0 + v1, v0 - v1, v0 + v1};
    float e0[4] = {-1.f, -1.f, 1.f, 1.f};
    float e1[4] = {-1.f, 1.f, -1.f, 1.f};
#define CSWAP(i, j)                                                   \
    if (lev[i] > lev[j]) {                                            \
      float t = lev[i]; lev[i] = lev[j]; lev[j] = t;                  \
      t = e0[i]; e0[i] = e0[j]; e0[j] = t;                            \
      t = e1[i]; e1[i] = e1[j]; e1[j] = t;                            \
    }
    CSWAP(0, 1) CSWAP(2, 3) CSWAP(0, 2) CSWAP(1, 3) CSWAP(1, 2)
#undef CSWAP
    const double A0 = e0[0], A1 = e0[1], A2 = e0[2], A3 = e0[3];
    const double B0 = e1[0], B1 = e1[1], B2 = e1[2], B3 = e1[3];
    const double N = (double)n;
    // telescoped sums over the monotone one-hot:
    //   sum f(idx)   = f0*N + (f1-f0)*C0 + (f2-f1)*C1 + (f3-f2)*C2
    //   sum f(idx)*w = f0*SW + (f1-f0)*SW0 + (f2-f1)*SW1 + (f3-f2)*SW2
    const double Sb0 = A0 * s + (A1 - A0) * s0 + (A2 - A1) * s1 + (A3 - A2) * s2;
    const double Sb1 = B0 * s + (B1 - B0) * s0 + (B2 - B1) * s1 + (B3 - B2) * s2;
    const double P0 = A0 * B0, P1 = A1 * B1, P2 = A2 * B2, P3 = A3 * B3;
    const double S01 = P0 * N + (P1 - P0) * c0 + (P2 - P1) * c1 + (P3 - P2) * c2;
    // A = [[N, S01],[S01, N]]; v = A^{-1} b; new_basis = 0.9*basis + 0.1*v
    const double det = N * N - S01 * S01;
    const double nv0 = (N * Sb0 - S01 * Sb1) / det;
    const double nv1 = (N * Sb1 - S01 * Sb0) / det;
    out_basis[0] = (float)(0.9 * (double)v0 + 0.1 * nv0);
    out_basis[1] = (float)(0.9 * (double)v1 + 0.1 * nv1);
  }
}

extern "C" void kernel_launch(void* const* d_in, const int* in_sizes, int n_in,
                              void* d_out, int out_size, void* d_ws, size_t ws_size,
                              hipStream_t stream) {
  const float* x = (const float*)d_in[0];
  const float* basis = (const float*)d_in[1];
  float* out = (float*)d_out;
  const int n = in_sizes[0];
  float* partials = (float*)d_ws;  // nblocks * 7 floats

  // clamp grid so partials always fit d_ws (2048*7*4B = 56 KB normally)
  int nblocks = NBLOCKS;
  const int maxb = (int)(ws_size / (7 * sizeof(float)));
  if (nblocks > maxb) nblocks = maxb;
  if (nblocks < 1) nblocks = 1;

  const int n4 = n / 4;
  lq_main<<<nblocks, NTHREADS, 0, stream>>>(x, basis, out, partials, n, n4, nblocks);
  lq_final<<<1, NTHREADS, 0, stream>>>(partials, basis, out + n, n, nblocks);
}